// Round 5
// baseline (1871.548 us; speedup 1.0000x reference)
//
#include <hip/hip_runtime.h>
#include <hip/hip_bf16.h>

// Problem constants (fixed shapes from the reference)
#define M_ROWS 25088   // 8 * 3136 embedding rows
#define N_CENT 4096    // centroids
#define K_DIM  1536    // feature dim (elements == bytes in fp8)
#define TILE   128
#define BK     128     // fp8 elements (=bytes) per K-chunk

typedef __attribute__((ext_vector_type(8))) int   int8v;    // f8f6f4 A/B frag (32 fp8)
typedef __attribute__((ext_vector_type(4))) int   int4v;
typedef __attribute__((ext_vector_type(4))) float floatx4;  // MFMA accumulator

typedef __attribute__((address_space(1))) const void gvoid;
typedef __attribute__((address_space(3))) void lvoid;

__device__ __forceinline__ void load_lds16(const void* g, void* l) {
    // async global->LDS, 16B per lane; LDS dest = wave-uniform base + lane*16
    __builtin_amdgcn_global_load_lds((gvoid*)g, (lvoid*)l, 16, 0, 0);
}

// Wave-per-row convert: fp32 -> fp8 e4m3 (OCP, HW cvt) + fp32 sum-of-squares.
// Block = 256 threads = 4 waves = 4 rows; 6 float4 loads/lane; shuffle-only
// reduction. Norms stay exact fp32 so only the dot term carries fp8 noise.
__global__ __launch_bounds__(256) void convert_rows(
    const float* __restrict__ src, unsigned int* __restrict__ dst,
    float* __restrict__ norms, unsigned int* __restrict__ minbuf, int nrows)
{
    const int row  = blockIdx.x * 4 + (threadIdx.x >> 6);
    const int lane = threadIdx.x & 63;
    if (row >= nrows) return;

    const float4* s = (const float4*)(src + (size_t)row * K_DIM);
    unsigned int* d = dst + (size_t)row * (K_DIM / 4);

    float4 v[6];
    #pragma unroll
    for (int j = 0; j < 6; ++j) v[j] = s[lane + j * 64];   // 6 loads in flight

    float ssq = 0.f;
    #pragma unroll
    for (int j = 0; j < 6; ++j) {
        ssq += v[j].x * v[j].x + v[j].y * v[j].y + v[j].z * v[j].z + v[j].w * v[j].w;
        int u = __builtin_amdgcn_cvt_pk_fp8_f32(v[j].x, v[j].y, 0, false);
        u     = __builtin_amdgcn_cvt_pk_fp8_f32(v[j].z, v[j].w, u, true);
        d[lane + j * 64] = (unsigned int)u;
    }

    #pragma unroll
    for (int off = 32; off >= 1; off >>= 1) ssq += __shfl_down(ssq, off, 64);
    if (lane == 0) {
        norms[row] = ssq;
        if (minbuf) minbuf[row] = 0x7F800000u;  // +inf bits (ws re-poisoned each launch)
    }
}

// 128x128 MX-fp8 MFMA GEMM tile (16x16x128 f8f6f4, unit E8M0 scales) with
// fused per-row min(dist^2) epilogue. A = embeds [M,K] fp8, B = centroids
// [N,K] fp8 (NT layout).
//
// LDS layout is rotation-swizzled: row R stores its 8 16B-chunks at slot
// (chunk + R) & 7 (row stride 128 B = exactly 32 banks; rotation gives
// 8-phase-floor frag reads). Swizzle is applied on the GLOBAL source address
// so global_load_lds's fixed lane->base+l*16 LDS mapping produces it; each
// 8-lane group still covers one contiguous 128-B global row (coalesced).
//
// R4 lesson: NEVER build frags by writing through a pointer-cast into a
// local ((int4v*)&a[im])[0] = ... — the alloca escapes mem2reg and the
// frags live in scratch (3 GB of spill traffic measured). Use
// __builtin_shufflevector to merge in SSA form.
__global__ __launch_bounds__(256, 3) void gemm_min(
    const unsigned char* __restrict__ A,
    const unsigned char* __restrict__ B,
    const float* __restrict__ nx,
    const float* __restrict__ nc,
    unsigned int* __restrict__ minbuf)
{
    __shared__ unsigned char sA[TILE * BK];   // 16 KB
    __shared__ unsigned char sB[TILE * BK];   // 16 KB

    const int tid  = threadIdx.x;
    const int wave = tid >> 6;
    const int lane = tid & 63;
    const int quad = lane >> 4;
    const int l15  = lane & 15;
    const int tile_n = blockIdx.x * TILE;
    const int tile_m = blockIdx.y * TILE;

    // Staging: one load = 64 lanes x 16 B = 8 rows x 128 B. Round r (0..3),
    // wave w -> LDS rows (r*4+w)*8..+8 (bytes (r*4+w)*1024). Lane l -> row
    // l>>3 within the group; global chunk = ((l&7) - (l>>3)) & 7 (rotation;
    // row-group bases are multiples of 8 so rotation amount is l>>3).
    const int srow   = lane >> 3;
    const int schunk = ((lane & 7) - srow) & 7;
    const unsigned char* aSrc = A + (size_t)(tile_m + wave * 8 + srow) * K_DIM + schunk * 16;
    const unsigned char* bSrc = B + (size_t)(tile_n + wave * 8 + srow) * K_DIM + schunk * 16;

    floatx4 acc[4][4];
    #pragma unroll
    for (int i = 0; i < 4; ++i)
        #pragma unroll
        for (int j = 0; j < 4; ++j)
            acc[i][j] = (floatx4){0.f, 0.f, 0.f, 0.f};

    const int wm = (wave >> 1) * 64;   // wave quadrant within 128x128
    const int wn = (wave & 1) * 64;

    // Frag read slots: lane (quad,m) wants k-bytes quad*32..+31 = chunks
    // 2q, 2q+1 of row m, stored at slots (chunk + m) & 7. m & 7 == l15 & 7
    // (wm, im*16 are multiples of 8), so slots are im-independent.
    const int s0 = (2 * quad + l15) & 7;
    const int s1 = (2 * quad + 1 + l15) & 7;

    for (int k0 = 0; k0 < K_DIM; k0 += BK) {
        #pragma unroll
        for (int r = 0; r < 4; ++r) {
            load_lds16(aSrc + (size_t)(r * 32) * K_DIM, (char*)sA + (r * 4 + wave) * 1024);
            load_lds16(bSrc + (size_t)(r * 32) * K_DIM, (char*)sB + (r * 4 + wave) * 1024);
        }
        __syncthreads();   // drains vmcnt -> tiles visible

        int8v a[4];
        #pragma unroll
        for (int im = 0; im < 4; ++im) {
            const unsigned char* p = sA + (wm + im * 16 + l15) * BK;
            const int4v lo = *(const int4v*)(p + s0 * 16);
            const int4v hi = *(const int4v*)(p + s1 * 16);
            a[im] = __builtin_shufflevector(lo, hi, 0, 1, 2, 3, 4, 5, 6, 7);
        }
        #pragma unroll
        for (int in = 0; in < 4; ++in) {
            const unsigned char* p = sB + (wn + in * 16 + l15) * BK;
            const int4v lo = *(const int4v*)(p + s0 * 16);
            const int4v hi = *(const int4v*)(p + s1 * 16);
            const int8v b = __builtin_shufflevector(lo, hi, 0, 1, 2, 3, 4, 5, 6, 7);
            #pragma unroll
            for (int im = 0; im < 4; ++im)
                acc[im][in] = __builtin_amdgcn_mfma_scale_f32_16x16x128_f8f6f4(
                    a[im], b, acc[im][in],
                    0 /*cbsz: A=e4m3*/, 0 /*blgp: B=e4m3*/,
                    0, 0x7F7F7F7F,   // scale_a opsel, E8M0 1.0 in every byte
                    0, 0x7F7F7F7F);  // scale_b
        }

        __syncthreads();   // all waves done reading before next overwrite
        aSrc += BK;
        bSrc += BK;
    }

    // Epilogue: dist^2 = nx[m] + nc[p] - 2*dot. Per-row min over this block's
    // 128 columns, then one atomicMin (positive-float uint bits) per row.
    // C/D layout is shape-determined, dtype-independent (guide m121-m128):
    // row = quad*4 + i, col = l15 within each 16x16 tile.
    float cn[4];
    #pragma unroll
    for (int in = 0; in < 4; ++in) cn[in] = nc[tile_n + wn + in * 16 + l15];

    #pragma unroll
    for (int im = 0; im < 4; ++im) {
        #pragma unroll
        for (int i = 0; i < 4; ++i) {
            float v =        cn[0] - 2.f * acc[im][0][i];
            v = fminf(v, cn[1] - 2.f * acc[im][1][i]);
            v = fminf(v, cn[2] - 2.f * acc[im][2][i]);
            v = fminf(v, cn[3] - 2.f * acc[im][3][i]);
            // min across the 16 lanes sharing this output row
            v = fminf(v, __shfl_xor(v, 8, 16));
            v = fminf(v, __shfl_xor(v, 4, 16));
            v = fminf(v, __shfl_xor(v, 2, 16));
            v = fminf(v, __shfl_xor(v, 1, 16));
            if (l15 == 0) {
                const int r = tile_m + wm + im * 16 + quad * 4 + i;
                atomicMin(&minbuf[r], __float_as_uint(v + nx[r]));
            }
        }
    }
}

__global__ void finalize_kernel(const unsigned int* __restrict__ minbuf,
                                float* __restrict__ out)
{
    const int i = blockIdx.x * 256 + threadIdx.x;
    if (i == 0) out[0] = 0.0f;                 // loss (eval mode)
    if (i < M_ROWS) out[1 + i] = sqrtf(__uint_as_float(minbuf[i]));
}

extern "C" void kernel_launch(void* const* d_in, const int* in_sizes, int n_in,
                              void* d_out, int out_size, void* d_ws, size_t ws_size,
                              hipStream_t stream)
{
    const float* embeds = (const float*)d_in[0];   // [8, 3136, 1536] fp32
    const float* cents  = (const float*)d_in[1];   // [4096, 1536] fp32
    float* out = (float*)d_out;                    // [1 + 25088] fp32

    char* ws = (char*)d_ws;
    const size_t offA   = 0;                                   // 38,535,168 B (fp8)
    const size_t offB   = offA + (size_t)M_ROWS * K_DIM;       //  6,291,456 B (fp8)
    const size_t offNx  = offB + (size_t)N_CENT * K_DIM;       //    100,352 B
    const size_t offNc  = offNx + (size_t)M_ROWS * 4;          //     16,384 B
    const size_t offMin = offNc + (size_t)N_CENT * 4;          //    100,352 B

    unsigned char* A8 = (unsigned char*)(ws + offA);
    unsigned char* B8 = (unsigned char*)(ws + offB);
    float* nx = (float*)(ws + offNx);
    float* nc = (float*)(ws + offNc);
    unsigned int* minbuf = (unsigned int*)(ws + offMin);

    convert_rows<<<M_ROWS / 4, 256, 0, stream>>>(embeds, (unsigned int*)A8, nx, minbuf, M_ROWS);
    convert_rows<<<N_CENT / 4, 256, 0, stream>>>(cents, (unsigned int*)B8, nc, nullptr, N_CENT);

    dim3 grid(N_CENT / TILE, M_ROWS / TILE);   // x = column tiles (fast) for A-tile L2/LLC reuse
    gemm_min<<<grid, 256, 0, stream>>>(A8, B8, nx, nc, minbuf);

    finalize_kernel<<<(M_ROWS + 255) / 256, 256, 0, stream>>>(minbuf, out);
}

// Round 6
// 766.896 us; speedup vs baseline: 2.4404x; 2.4404x over previous
//
#include <hip/hip_runtime.h>
#include <hip/hip_bf16.h>

// Problem constants (fixed shapes from the reference)
#define M_ROWS 25088   // 8 * 3136 embedding rows
#define N_CENT 4096    // centroids
#define K_DIM  1536    // feature dim (elements == bytes in fp8)
#define TILE   128
#define BK     128     // fp8 elements (=bytes) per K-chunk

typedef __attribute__((ext_vector_type(8))) int   int8v;    // f8f6f4 A/B frag (32 fp8)
typedef __attribute__((ext_vector_type(4))) float floatx4;  // MFMA accumulator

typedef __attribute__((address_space(1))) const void gvoid;
typedef __attribute__((address_space(3))) void lvoid;

__device__ __forceinline__ void load_lds16(const void* g, void* l) {
    // async global->LDS, 16B per lane; LDS dest = wave-uniform base + lane*16
    __builtin_amdgcn_global_load_lds((gvoid*)g, (lvoid*)l, 16, 0, 0);
}

// Wave-per-row convert: fp32 -> fp8 e4m3 (OCP, HW cvt) + fp32 sum-of-squares.
// Block = 256 threads = 4 waves = 4 rows; 6 float4 loads/lane; shuffle-only
// reduction. Norms stay exact fp32 so only the dot term carries fp8 noise.
__global__ __launch_bounds__(256) void convert_rows(
    const float* __restrict__ src, unsigned int* __restrict__ dst,
    float* __restrict__ norms, unsigned int* __restrict__ minbuf, int nrows)
{
    const int row  = blockIdx.x * 4 + (threadIdx.x >> 6);
    const int lane = threadIdx.x & 63;
    if (row >= nrows) return;

    const float4* s = (const float4*)(src + (size_t)row * K_DIM);
    unsigned int* d = dst + (size_t)row * (K_DIM / 4);

    float4 v[6];
    #pragma unroll
    for (int j = 0; j < 6; ++j) v[j] = s[lane + j * 64];   // 6 loads in flight

    float ssq = 0.f;
    #pragma unroll
    for (int j = 0; j < 6; ++j) {
        ssq += v[j].x * v[j].x + v[j].y * v[j].y + v[j].z * v[j].z + v[j].w * v[j].w;
        int u = __builtin_amdgcn_cvt_pk_fp8_f32(v[j].x, v[j].y, 0, false);
        u     = __builtin_amdgcn_cvt_pk_fp8_f32(v[j].z, v[j].w, u, true);
        d[lane + j * 64] = (unsigned int)u;
    }

    #pragma unroll
    for (int off = 32; off >= 1; off >>= 1) ssq += __shfl_down(ssq, off, 64);
    if (lane == 0) {
        norms[row] = ssq;
        if (minbuf) minbuf[row] = 0x7F800000u;  // +inf bits (ws re-poisoned each launch)
    }
}

// 128x128 MX-fp8 MFMA GEMM tile (16x16x128 f8f6f4, unit E8M0 scales) with
// fused per-row min(dist^2) epilogue. A = embeds [M,K] fp8, B = centroids
// [N,K] fp8 (NT layout).
//
// LDS layout: plain row-major [128 rows][128 B]. Lane (quad q, m=l15) needs
// A-row m k-bytes q*32..+31 -> ONE contiguous 32-byte load at row*128+q*32
// (single SSA int8v load, no merge). R4 built frags by writing through a
// pointer-cast into a local and R5 by shufflevector-merging two int4v loads;
// BOTH produced identical ~3 GB scratch traffic (frags never reached
// registers). This version eliminates the two-part merge entirely — the
// discriminating test between "merge defeats regalloc" and "builtin lowering
// is broken". Known cost: contiguous-32B frag reads use only 16 of 32 banks
// per ds_read_b128 half (2x LDS phases vs the 8-phase floor) — acceptable;
// re-add a swizzle later only if the spill is gone.
__global__ __launch_bounds__(256) void gemm_min(
    const unsigned char* __restrict__ A,
    const unsigned char* __restrict__ B,
    const float* __restrict__ nx,
    const float* __restrict__ nc,
    unsigned int* __restrict__ minbuf)
{
    __shared__ unsigned char sA[TILE * BK];   // 16 KB
    __shared__ unsigned char sB[TILE * BK];   // 16 KB

    const int tid  = threadIdx.x;
    const int wave = tid >> 6;
    const int lane = tid & 63;
    const int quad = lane >> 4;
    const int l15  = lane & 15;
    const int tile_n = blockIdx.x * TILE;
    const int tile_m = blockIdx.y * TILE;

    // Staging: one load = 64 lanes x 16 B = 8 rows x 128 B (contiguous in
    // both LDS and per-row global). Round r (0..3), wave w -> LDS rows
    // (r*4+w)*8..+8 (bytes (r*4+w)*1024). Lane l -> row l>>3 within the
    // group, chunk (l&7)*16.
    const int srow   = lane >> 3;
    const int schunk = (lane & 7) * 16;
    const unsigned char* aSrc = A + (size_t)(tile_m + wave * 8 + srow) * K_DIM + schunk;
    const unsigned char* bSrc = B + (size_t)(tile_n + wave * 8 + srow) * K_DIM + schunk;

    floatx4 acc[4][4];
    #pragma unroll
    for (int i = 0; i < 4; ++i)
        #pragma unroll
        for (int j = 0; j < 4; ++j)
            acc[i][j] = (floatx4){0.f, 0.f, 0.f, 0.f};

    const int wm = (wave >> 1) * 64;   // wave quadrant within 128x128
    const int wn = (wave & 1) * 64;

    for (int k0 = 0; k0 < K_DIM; k0 += BK) {
        #pragma unroll
        for (int r = 0; r < 4; ++r) {
            load_lds16(aSrc + (size_t)(r * 32) * K_DIM, (char*)sA + (r * 4 + wave) * 1024);
            load_lds16(bSrc + (size_t)(r * 32) * K_DIM, (char*)sB + (r * 4 + wave) * 1024);
        }
        __syncthreads();   // drains vmcnt -> tiles visible

        int8v a[4];
        #pragma unroll
        for (int im = 0; im < 4; ++im)
            a[im] = *(const int8v*)(sA + (wm + im * 16 + l15) * BK + quad * 32);

        #pragma unroll
        for (int in = 0; in < 4; ++in) {
            const int8v b = *(const int8v*)(sB + (wn + in * 16 + l15) * BK + quad * 32);
            #pragma unroll
            for (int im = 0; im < 4; ++im)
                acc[im][in] = __builtin_amdgcn_mfma_scale_f32_16x16x128_f8f6f4(
                    a[im], b, acc[im][in],
                    0 /*cbsz: A=e4m3*/, 0 /*blgp: B=e4m3*/,
                    0, 0x7F7F7F7F,   // scale_a opsel, E8M0 1.0 in every byte
                    0, 0x7F7F7F7F);  // scale_b
        }

        __syncthreads();   // all waves done reading before next overwrite
        aSrc += BK;
        bSrc += BK;
    }

    // Epilogue: dist^2 = nx[m] + nc[p] - 2*dot. Per-row min over this block's
    // 128 columns, then one atomicMin (positive-float uint bits) per row.
    // C/D layout is shape-determined, dtype-independent (guide m121-m128):
    // row = quad*4 + i, col = l15 within each 16x16 tile.
    float cn[4];
    #pragma unroll
    for (int in = 0; in < 4; ++in) cn[in] = nc[tile_n + wn + in * 16 + l15];

    #pragma unroll
    for (int im = 0; im < 4; ++im) {
        #pragma unroll
        for (int i = 0; i < 4; ++i) {
            float v =        cn[0] - 2.f * acc[im][0][i];
            v = fminf(v, cn[1] - 2.f * acc[im][1][i]);
            v = fminf(v, cn[2] - 2.f * acc[im][2][i]);
            v = fminf(v, cn[3] - 2.f * acc[im][3][i]);
            // min across the 16 lanes sharing this output row
            v = fminf(v, __shfl_xor(v, 8, 16));
            v = fminf(v, __shfl_xor(v, 4, 16));
            v = fminf(v, __shfl_xor(v, 2, 16));
            v = fminf(v, __shfl_xor(v, 1, 16));
            if (l15 == 0) {
                const int r = tile_m + wm + im * 16 + quad * 4 + i;
                atomicMin(&minbuf[r], __float_as_uint(v + nx[r]));
            }
        }
    }
}

__global__ void finalize_kernel(const unsigned int* __restrict__ minbuf,
                                float* __restrict__ out)
{
    const int i = blockIdx.x * 256 + threadIdx.x;
    if (i == 0) out[0] = 0.0f;                 // loss (eval mode)
    if (i < M_ROWS) out[1 + i] = sqrtf(__uint_as_float(minbuf[i]));
}

extern "C" void kernel_launch(void* const* d_in, const int* in_sizes, int n_in,
                              void* d_out, int out_size, void* d_ws, size_t ws_size,
                              hipStream_t stream)
{
    const float* embeds = (const float*)d_in[0];   // [8, 3136, 1536] fp32
    const float* cents  = (const float*)d_in[1];   // [4096, 1536] fp32
    float* out = (float*)d_out;                    // [1 + 25088] fp32

    char* ws = (char*)d_ws;
    const size_t offA   = 0;                                   // 38,535,168 B (fp8)
    const size_t offB   = offA + (size_t)M_ROWS * K_DIM;       //  6,291,456 B (fp8)
    const size_t offNx  = offB + (size_t)N_CENT * K_DIM;       //    100,352 B
    const size_t offNc  = offNx + (size_t)M_ROWS * 4;          //     16,384 B
    const size_t offMin = offNc + (size_t)N_CENT * 4;          //    100,352 B

    unsigned char* A8 = (unsigned char*)(ws + offA);
    unsigned char* B8 = (unsigned char*)(ws + offB);
    float* nx = (float*)(ws + offNx);
    float* nc = (float*)(ws + offNc);
    unsigned int* minbuf = (unsigned int*)(ws + offMin);

    convert_rows<<<M_ROWS / 4, 256, 0, stream>>>(embeds, (unsigned int*)A8, nx, minbuf, M_ROWS);
    convert_rows<<<N_CENT / 4, 256, 0, stream>>>(cents, (unsigned int*)B8, nc, nullptr, N_CENT);

    dim3 grid(N_CENT / TILE, M_ROWS / TILE);   // x = column tiles (fast) for A-tile L2/LLC reuse
    gemm_min<<<grid, 256, 0, stream>>>(A8, B8, nx, nc, minbuf);

    finalize_kernel<<<(M_ROWS + 255) / 256, 256, 0, stream>>>(minbuf, out);
}

// Round 7
// 476.686 us; speedup vs baseline: 3.9262x; 1.6088x over previous
//
#include <hip/hip_runtime.h>
#include <hip/hip_bf16.h>

// Problem constants (fixed shapes from the reference)
#define M_ROWS 25088   // 8 * 3136 embedding rows
#define N_CENT 4096    // centroids
#define K_DIM  1536    // feature dim (elements == bytes in fp8)
#define TILE   128
#define BK     128     // fp8 elements (=bytes) per K-chunk

typedef __attribute__((ext_vector_type(8))) int   int8v;    // f8f6f4 A/B frag (32 fp8)
typedef __attribute__((ext_vector_type(4))) float floatx4;  // MFMA accumulator

typedef __attribute__((address_space(1))) const void gvoid;
typedef __attribute__((address_space(3))) void lvoid;

__device__ __forceinline__ void load_lds16(const void* g, void* l) {
    // async global->LDS, 16B per lane; LDS dest = wave-uniform base + lane*16
    __builtin_amdgcn_global_load_lds((gvoid*)g, (lvoid*)l, 16, 0, 0);
}

// Wave-per-row convert: fp32 -> fp8 e4m3 (OCP, HW cvt) + fp32 sum-of-squares.
// Block = 256 threads = 4 waves = 4 rows; 6 float4 loads/lane; shuffle-only
// reduction. Norms stay exact fp32 so only the dot term carries fp8 noise.
__global__ __launch_bounds__(256) void convert_rows(
    const float* __restrict__ src, unsigned int* __restrict__ dst,
    float* __restrict__ norms, unsigned int* __restrict__ minbuf, int nrows)
{
    const int row  = blockIdx.x * 4 + (threadIdx.x >> 6);
    const int lane = threadIdx.x & 63;
    if (row >= nrows) return;

    const float4* s = (const float4*)(src + (size_t)row * K_DIM);
    unsigned int* d = dst + (size_t)row * (K_DIM / 4);

    float4 v[6];
    #pragma unroll
    for (int j = 0; j < 6; ++j) v[j] = s[lane + j * 64];   // 6 loads in flight

    float ssq = 0.f;
    #pragma unroll
    for (int j = 0; j < 6; ++j) {
        ssq += v[j].x * v[j].x + v[j].y * v[j].y + v[j].z * v[j].z + v[j].w * v[j].w;
        int u = __builtin_amdgcn_cvt_pk_fp8_f32(v[j].x, v[j].y, 0, false);
        u     = __builtin_amdgcn_cvt_pk_fp8_f32(v[j].z, v[j].w, u, true);
        d[lane + j * 64] = (unsigned int)u;
    }

    #pragma unroll
    for (int off = 32; off >= 1; off >>= 1) ssq += __shfl_down(ssq, off, 64);
    if (lane == 0) {
        norms[row] = ssq;
        if (minbuf) minbuf[row] = 0x7F800000u;  // +inf bits (ws re-poisoned each launch)
    }
}

// 128x128 MX-fp8 MFMA GEMM tile (16x16x128 f8f6f4, unit E8M0 scales) with
// fused per-row min(dist^2) epilogue. A = embeds [M,K] fp8, B = centroids
// [N,K] fp8 (NT layout).
//
// LDS layout: plain row-major [128 rows][128 B]; frag = ONE contiguous 32-byte
// SSA load (single int8v — R4/R5's two-load merge caused 3 GB of scratch
// spill; R6 proved the single load is spill-clean).
//
// R6 lesson: the K-loop trip count (12) is a compile-time constant and the
// compiler FULLY UNROLLED it, hoisting loads across iterations -> VGPR 256
// (maxed) + 343 MB spill + 1 wave/SIMD (11.5% occupancy). `#pragma unroll 1`
// keeps the loop rolled so live ranges stay within one iteration.
//
// Known remaining cost (attack next if this lands): contiguous-32B frag reads
// put 16 lanes on each 4-bank group -> 2x LDS phase floor (~94 us/CU extra,
// SQ_LDS_BANK_CONFLICT 57.8M).
__global__ __launch_bounds__(256) void gemm_min(
    const unsigned char* __restrict__ A,
    const unsigned char* __restrict__ B,
    const float* __restrict__ nx,
    const float* __restrict__ nc,
    unsigned int* __restrict__ minbuf)
{
    __shared__ unsigned char sA[TILE * BK];   // 16 KB
    __shared__ unsigned char sB[TILE * BK];   // 16 KB

    const int tid  = threadIdx.x;
    const int wave = tid >> 6;
    const int lane = tid & 63;
    const int quad = lane >> 4;
    const int l15  = lane & 15;
    const int tile_n = blockIdx.x * TILE;
    const int tile_m = blockIdx.y * TILE;

    // Staging: one load = 64 lanes x 16 B = 8 rows x 128 B (contiguous in
    // both LDS and per-row global). Round r (0..3), wave w -> LDS rows
    // (r*4+w)*8..+8 (bytes (r*4+w)*1024). Lane l -> row l>>3 within the
    // group, chunk (l&7)*16.
    const int srow   = lane >> 3;
    const int schunk = (lane & 7) * 16;
    const unsigned char* aSrc = A + (size_t)(tile_m + wave * 8 + srow) * K_DIM + schunk;
    const unsigned char* bSrc = B + (size_t)(tile_n + wave * 8 + srow) * K_DIM + schunk;

    floatx4 acc[4][4];
    #pragma unroll
    for (int i = 0; i < 4; ++i)
        #pragma unroll
        for (int j = 0; j < 4; ++j)
            acc[i][j] = (floatx4){0.f, 0.f, 0.f, 0.f};

    const int wm = (wave >> 1) * 64;   // wave quadrant within 128x128
    const int wn = (wave & 1) * 64;

    #pragma unroll 1   // MUST stay rolled: full unroll (trip=12) maxes VGPRs and spills (R6)
    for (int k0 = 0; k0 < K_DIM; k0 += BK) {
        #pragma unroll
        for (int r = 0; r < 4; ++r) {
            load_lds16(aSrc + (size_t)(r * 32) * K_DIM, (char*)sA + (r * 4 + wave) * 1024);
            load_lds16(bSrc + (size_t)(r * 32) * K_DIM, (char*)sB + (r * 4 + wave) * 1024);
        }
        __syncthreads();   // drains vmcnt -> tiles visible

        int8v a[4];
        #pragma unroll
        for (int im = 0; im < 4; ++im)
            a[im] = *(const int8v*)(sA + (wm + im * 16 + l15) * BK + quad * 32);

        #pragma unroll
        for (int in = 0; in < 4; ++in) {
            const int8v b = *(const int8v*)(sB + (wn + in * 16 + l15) * BK + quad * 32);
            #pragma unroll
            for (int im = 0; im < 4; ++im)
                acc[im][in] = __builtin_amdgcn_mfma_scale_f32_16x16x128_f8f6f4(
                    a[im], b, acc[im][in],
                    0 /*cbsz: A=e4m3*/, 0 /*blgp: B=e4m3*/,
                    0, 0x7F7F7F7F,   // scale_a opsel, E8M0 1.0 in every byte
                    0, 0x7F7F7F7F);  // scale_b
        }

        __syncthreads();   // all waves done reading before next overwrite
        aSrc += BK;
        bSrc += BK;
    }

    // Epilogue: dist^2 = nx[m] + nc[p] - 2*dot. Per-row min over this block's
    // 128 columns, then one atomicMin (positive-float uint bits) per row.
    // C/D layout is shape-determined, dtype-independent (guide m121-m128):
    // row = quad*4 + i, col = l15 within each 16x16 tile.
    float cn[4];
    #pragma unroll
    for (int in = 0; in < 4; ++in) cn[in] = nc[tile_n + wn + in * 16 + l15];

    #pragma unroll
    for (int im = 0; im < 4; ++im) {
        #pragma unroll
        for (int i = 0; i < 4; ++i) {
            float v =        cn[0] - 2.f * acc[im][0][i];
            v = fminf(v, cn[1] - 2.f * acc[im][1][i]);
            v = fminf(v, cn[2] - 2.f * acc[im][2][i]);
            v = fminf(v, cn[3] - 2.f * acc[im][3][i]);
            // min across the 16 lanes sharing this output row
            v = fminf(v, __shfl_xor(v, 8, 16));
            v = fminf(v, __shfl_xor(v, 4, 16));
            v = fminf(v, __shfl_xor(v, 2, 16));
            v = fminf(v, __shfl_xor(v, 1, 16));
            if (l15 == 0) {
                const int r = tile_m + wm + im * 16 + quad * 4 + i;
                atomicMin(&minbuf[r], __float_as_uint(v + nx[r]));
            }
        }
    }
}

__global__ void finalize_kernel(const unsigned int* __restrict__ minbuf,
                                float* __restrict__ out)
{
    const int i = blockIdx.x * 256 + threadIdx.x;
    if (i == 0) out[0] = 0.0f;                 // loss (eval mode)
    if (i < M_ROWS) out[1 + i] = sqrtf(__uint_as_float(minbuf[i]));
}

extern "C" void kernel_launch(void* const* d_in, const int* in_sizes, int n_in,
                              void* d_out, int out_size, void* d_ws, size_t ws_size,
                              hipStream_t stream)
{
    const float* embeds = (const float*)d_in[0];   // [8, 3136, 1536] fp32
    const float* cents  = (const float*)d_in[1];   // [4096, 1536] fp32
    float* out = (float*)d_out;                    // [1 + 25088] fp32

    char* ws = (char*)d_ws;
    const size_t offA   = 0;                                   // 38,535,168 B (fp8)
    const size_t offB   = offA + (size_t)M_ROWS * K_DIM;       //  6,291,456 B (fp8)
    const size_t offNx  = offB + (size_t)N_CENT * K_DIM;       //    100,352 B
    const size_t offNc  = offNx + (size_t)M_ROWS * 4;          //     16,384 B
    const size_t offMin = offNc + (size_t)N_CENT * 4;          //    100,352 B

    unsigned char* A8 = (unsigned char*)(ws + offA);
    unsigned char* B8 = (unsigned char*)(ws + offB);
    float* nx = (float*)(ws + offNx);
    float* nc = (float*)(ws + offNc);
    unsigned int* minbuf = (unsigned int*)(ws + offMin);

    convert_rows<<<M_ROWS / 4, 256, 0, stream>>>(embeds, (unsigned int*)A8, nx, minbuf, M_ROWS);
    convert_rows<<<N_CENT / 4, 256, 0, stream>>>(cents, (unsigned int*)B8, nc, nullptr, N_CENT);

    dim3 grid(N_CENT / TILE, M_ROWS / TILE);   // x = column tiles (fast) for A-tile L2/LLC reuse
    gemm_min<<<grid, 256, 0, stream>>>(A8, B8, nx, nc, minbuf);

    finalize_kernel<<<(M_ROWS + 255) / 256, 256, 0, stream>>>(minbuf, out);
}

// Round 8
// 436.477 us; speedup vs baseline: 4.2878x; 1.0921x over previous
//
#include <hip/hip_runtime.h>
#include <hip/hip_bf16.h>

// Problem constants (fixed shapes from the reference)
#define M_ROWS 25088   // 8 * 3136 embedding rows
#define N_CENT 4096    // centroids
#define K_DIM  1536    // feature dim (elements == bytes in fp8)
#define TILE   128
#define BK     128     // fp8 elements (=bytes) per K-chunk

typedef __attribute__((ext_vector_type(8))) int   int8v;    // f8f6f4 A/B frag (32 fp8)
typedef __attribute__((ext_vector_type(4))) int   int4v;
typedef __attribute__((ext_vector_type(4))) float floatx4;  // MFMA accumulator

typedef __attribute__((address_space(1))) const void gvoid;
typedef __attribute__((address_space(3))) void lvoid;

__device__ __forceinline__ void load_lds16(const void* g, void* l) {
    // async global->LDS, 16B per lane; LDS dest = wave-uniform base + lane*16
    __builtin_amdgcn_global_load_lds((gvoid*)g, (lvoid*)l, 16, 0, 0);
}

// Wave-per-row convert: fp32 -> fp8 e4m3 (OCP, HW cvt) + fp32 sum-of-squares.
// Block = 256 threads = 4 waves = 4 rows; 6 float4 loads/lane; shuffle-only
// reduction. Norms stay exact fp32 so only the dot term carries fp8 noise.
__global__ __launch_bounds__(256) void convert_rows(
    const float* __restrict__ src, unsigned int* __restrict__ dst,
    float* __restrict__ norms, unsigned int* __restrict__ minbuf, int nrows)
{
    const int row  = blockIdx.x * 4 + (threadIdx.x >> 6);
    const int lane = threadIdx.x & 63;
    if (row >= nrows) return;

    const float4* s = (const float4*)(src + (size_t)row * K_DIM);
    unsigned int* d = dst + (size_t)row * (K_DIM / 4);

    float4 v[6];
    #pragma unroll
    for (int j = 0; j < 6; ++j) v[j] = s[lane + j * 64];   // 6 loads in flight

    float ssq = 0.f;
    #pragma unroll
    for (int j = 0; j < 6; ++j) {
        ssq += v[j].x * v[j].x + v[j].y * v[j].y + v[j].z * v[j].z + v[j].w * v[j].w;
        int u = __builtin_amdgcn_cvt_pk_fp8_f32(v[j].x, v[j].y, 0, false);
        u     = __builtin_amdgcn_cvt_pk_fp8_f32(v[j].z, v[j].w, u, true);
        d[lane + j * 64] = (unsigned int)u;
    }

    #pragma unroll
    for (int off = 32; off >= 1; off >>= 1) ssq += __shfl_down(ssq, off, 64);
    if (lane == 0) {
        norms[row] = ssq;
        if (minbuf) minbuf[row] = 0x7F800000u;  // +inf bits (ws re-poisoned each launch)
    }
}

// 128x128 MX-fp8 MFMA GEMM tile (16x16x128 f8f6f4, unit E8M0 scales) with
// fused per-row min(dist^2) epilogue. A = embeds [M,K] fp8, B = centroids
// [N,K] fp8 (NT layout).
//
// LDS layout: rotation-swizzled row-major [128 rows][8 slots x 16 B]: row R's
// chunk c sits at slot (c + R) & 7. Row stride 128 B = exactly 32 banks, so
// UNswizzled frag reads put all 16 lanes of a quad on one 4-bank group (2x
// phase floor; R7 measured 57.8M conflict cycles = the full 12->24 cyc/b128
// delta). With the rotation, a quad's 16 lanes spread over all 8 slots
// (2 lanes/slot = free, m136). Swizzle is applied on the GLOBAL source
// address so global_load_lds's fixed lane->base+l*16 mapping produces it;
// each 8-lane group still covers one contiguous 128-B global row.
//
// Hard-won codegen rules (R4-R7):
//  - `#pragma unroll 1` on the K-loop is MANDATORY: trip=12 is compile-time,
//    full unroll maxes VGPRs (256) and spills ~3 GB to scratch.
//  - Frag construction must be SSA (loads + shufflevector merge). Never
//    write through a pointer-cast into a local array.
__global__ __launch_bounds__(256) void gemm_min(
    const unsigned char* __restrict__ A,
    const unsigned char* __restrict__ B,
    const float* __restrict__ nx,
    const float* __restrict__ nc,
    unsigned int* __restrict__ minbuf)
{
    __shared__ unsigned char sA[TILE * BK];   // 16 KB
    __shared__ unsigned char sB[TILE * BK];   // 16 KB

    const int tid  = threadIdx.x;
    const int wave = tid >> 6;
    const int lane = tid & 63;
    const int quad = lane >> 4;
    const int l15  = lane & 15;
    const int tile_n = blockIdx.x * TILE;
    const int tile_m = blockIdx.y * TILE;

    // Staging: one load = 64 lanes x 16 B = 8 rows x 128 B. Round r (0..3),
    // wave w -> LDS rows (r*4+w)*8..+8 (bytes (r*4+w)*1024). Lane l -> row
    // l>>3 within the group; global chunk = ((l&7) - (l>>3)) & 7 (rotation;
    // row-group bases are multiples of 8 so rotation amount is l>>3).
    const int srow   = lane >> 3;
    const int schunk = ((lane & 7) - srow) & 7;
    const unsigned char* aSrc = A + (size_t)(tile_m + wave * 8 + srow) * K_DIM + schunk * 16;
    const unsigned char* bSrc = B + (size_t)(tile_n + wave * 8 + srow) * K_DIM + schunk * 16;

    floatx4 acc[4][4];
    #pragma unroll
    for (int i = 0; i < 4; ++i)
        #pragma unroll
        for (int j = 0; j < 4; ++j)
            acc[i][j] = (floatx4){0.f, 0.f, 0.f, 0.f};

    const int wm = (wave >> 1) * 64;   // wave quadrant within 128x128
    const int wn = (wave & 1) * 64;

    // Frag read slots: lane (quad,m=l15) wants k-bytes quad*32..+31 = chunks
    // 2q, 2q+1 of row m, stored at slots (chunk + m) & 7. m & 7 == l15 & 7
    // (wm, im*16 are multiples of 8), so slots are im-independent.
    const int s0 = (2 * quad + l15) & 7;
    const int s1 = (2 * quad + 1 + l15) & 7;

    #pragma unroll 1   // MUST stay rolled: full unroll (trip=12) maxes VGPRs and spills (R6)
    for (int k0 = 0; k0 < K_DIM; k0 += BK) {
        #pragma unroll
        for (int r = 0; r < 4; ++r) {
            load_lds16(aSrc + (size_t)(r * 32) * K_DIM, (char*)sA + (r * 4 + wave) * 1024);
            load_lds16(bSrc + (size_t)(r * 32) * K_DIM, (char*)sB + (r * 4 + wave) * 1024);
        }
        __syncthreads();   // drains vmcnt -> tiles visible

        int8v a[4];
        #pragma unroll
        for (int im = 0; im < 4; ++im) {
            const unsigned char* p = sA + (wm + im * 16 + l15) * BK;
            const int4v lo = *(const int4v*)(p + s0 * 16);
            const int4v hi = *(const int4v*)(p + s1 * 16);
            a[im] = __builtin_shufflevector(lo, hi, 0, 1, 2, 3, 4, 5, 6, 7);
        }

        #pragma unroll
        for (int in = 0; in < 4; ++in) {
            const unsigned char* p = sB + (wn + in * 16 + l15) * BK;
            const int4v lo = *(const int4v*)(p + s0 * 16);
            const int4v hi = *(const int4v*)(p + s1 * 16);
            const int8v b = __builtin_shufflevector(lo, hi, 0, 1, 2, 3, 4, 5, 6, 7);
            #pragma unroll
            for (int im = 0; im < 4; ++im)
                acc[im][in] = __builtin_amdgcn_mfma_scale_f32_16x16x128_f8f6f4(
                    a[im], b, acc[im][in],
                    0 /*cbsz: A=e4m3*/, 0 /*blgp: B=e4m3*/,
                    0, 0x7F7F7F7F,   // scale_a opsel, E8M0 1.0 in every byte
                    0, 0x7F7F7F7F);  // scale_b
        }

        __syncthreads();   // all waves done reading before next overwrite
        aSrc += BK;
        bSrc += BK;
    }

    // Epilogue: dist^2 = nx[m] + nc[p] - 2*dot. Per-row min over this block's
    // 128 columns, then one atomicMin (positive-float uint bits) per row.
    // C/D layout is shape-determined, dtype-independent (guide m121-m128):
    // row = quad*4 + i, col = l15 within each 16x16 tile.
    float cn[4];
    #pragma unroll
    for (int in = 0; in < 4; ++in) cn[in] = nc[tile_n + wn + in * 16 + l15];

    #pragma unroll
    for (int im = 0; im < 4; ++im) {
        #pragma unroll
        for (int i = 0; i < 4; ++i) {
            float v =        cn[0] - 2.f * acc[im][0][i];
            v = fminf(v, cn[1] - 2.f * acc[im][1][i]);
            v = fminf(v, cn[2] - 2.f * acc[im][2][i]);
            v = fminf(v, cn[3] - 2.f * acc[im][3][i]);
            // min across the 16 lanes sharing this output row
            v = fminf(v, __shfl_xor(v, 8, 16));
            v = fminf(v, __shfl_xor(v, 4, 16));
            v = fminf(v, __shfl_xor(v, 2, 16));
            v = fminf(v, __shfl_xor(v, 1, 16));
            if (l15 == 0) {
                const int r = tile_m + wm + im * 16 + quad * 4 + i;
                atomicMin(&minbuf[r], __float_as_uint(v + nx[r]));
            }
        }
    }
}

__global__ void finalize_kernel(const unsigned int* __restrict__ minbuf,
                                float* __restrict__ out)
{
    const int i = blockIdx.x * 256 + threadIdx.x;
    if (i == 0) out[0] = 0.0f;                 // loss (eval mode)
    if (i < M_ROWS) out[1 + i] = sqrtf(__uint_as_float(minbuf[i]));
}

extern "C" void kernel_launch(void* const* d_in, const int* in_sizes, int n_in,
                              void* d_out, int out_size, void* d_ws, size_t ws_size,
                              hipStream_t stream)
{
    const float* embeds = (const float*)d_in[0];   // [8, 3136, 1536] fp32
    const float* cents  = (const float*)d_in[1];   // [4096, 1536] fp32
    float* out = (float*)d_out;                    // [1 + 25088] fp32

    char* ws = (char*)d_ws;
    const size_t offA   = 0;                                   // 38,535,168 B (fp8)
    const size_t offB   = offA + (size_t)M_ROWS * K_DIM;       //  6,291,456 B (fp8)
    const size_t offNx  = offB + (size_t)N_CENT * K_DIM;       //    100,352 B
    const size_t offNc  = offNx + (size_t)M_ROWS * 4;          //     16,384 B
    const size_t offMin = offNc + (size_t)N_CENT * 4;          //    100,352 B

    unsigned char* A8 = (unsigned char*)(ws + offA);
    unsigned char* B8 = (unsigned char*)(ws + offB);
    float* nx = (float*)(ws + offNx);
    float* nc = (float*)(ws + offNc);
    unsigned int* minbuf = (unsigned int*)(ws + offMin);

    convert_rows<<<M_ROWS / 4, 256, 0, stream>>>(embeds, (unsigned int*)A8, nx, minbuf, M_ROWS);
    convert_rows<<<N_CENT / 4, 256, 0, stream>>>(cents, (unsigned int*)B8, nc, nullptr, N_CENT);

    dim3 grid(N_CENT / TILE, M_ROWS / TILE);   // x = column tiles (fast) for A-tile L2/LLC reuse
    gemm_min<<<grid, 256, 0, stream>>>(A8, B8, nx, nc, minbuf);

    finalize_kernel<<<(M_ROWS + 255) / 256, 256, 0, stream>>>(minbuf, out);
}